// Round 1
// baseline (707.766 us; speedup 1.0000x reference)
//
#include <hip/hip_runtime.h>
#include <math.h>

#define SEQ 2048
#define DM 1024
#define NH 16
#define DKV 64
#define MTOT 4096  /* BATCH*SEQ */

typedef __attribute__((ext_vector_type(8))) short bf16x8;
typedef __attribute__((ext_vector_type(4))) float f32x4;
typedef unsigned short ushort_t;

__device__ __forceinline__ short f2bf(float f) {
    union { float f; unsigned u; } v; v.f = f;
    unsigned r = v.u + 0x7fffu + ((v.u >> 16) & 1u);
    return (short)(r >> 16);
}

// ---------------- RoPE tables: cos/sin[pos][i], pos<2048, i<32 ----------------
__global__ void rope_table_kernel(float* __restrict__ cos_t, float* __restrict__ sin_t) {
    int tid = blockIdx.x * blockDim.x + threadIdx.x;  // 0..65535
    int i = tid & 31, pos = tid >> 5;
    double freq = pow(10000.0, -(double)(2 * i) / 64.0);
    double ang = (double)pos * freq;
    cos_t[tid] = (float)cos(ang);
    sin_t[tid] = (float)sin(ang);
}

// ---------------- QKV projection + RoPE ----------------
// grid (DM/64, MTOT/64, 3), block 256. Each wave: 32x32 output tile via 2x2 MFMA tiles.
// out[b,s,o] = sum_i x[b,s,i] * w[o,i]   (C = X * W^T, W row-major [o][i])
__global__ __launch_bounds__(256) void proj_qkv_kernel(
    const float* __restrict__ x,
    const float* __restrict__ wq, const float* __restrict__ wk, const float* __restrict__ wv,
    const float* __restrict__ cos_t, const float* __restrict__ sin_t,
    const int* __restrict__ tokpos,
    ushort_t* __restrict__ Qo, ushort_t* __restrict__ Ko, ushort_t* __restrict__ Vo)
{
    const int z = blockIdx.z;
    const float* w = (z == 0) ? wq : (z == 1) ? wk : wv;
    ushort_t* dst = (z == 0) ? Qo : (z == 1) ? Ko : Vo;
    const bool do_rope = (z != 2);

    const int lane = threadIdx.x & 63;
    const int wave = threadIdx.x >> 6;
    const int quad = lane >> 4, l16 = lane & 15;
    const int Mb = blockIdx.y * 64 + (wave >> 1) * 32;
    const int Nb = blockIdx.x * 64 + (wave & 1) * 32;

    f32x4 acc[2][2] = {};

    for (int k0 = 0; k0 < DM; k0 += 32) {
        bf16x8 a[2], b[2];
        #pragma unroll
        for (int mt = 0; mt < 2; ++mt) {
            const float* p = x + (size_t)(Mb + mt * 16 + l16) * DM + k0 + quad * 8;
            f32x4 p0 = *(const f32x4*)p;
            f32x4 p1 = *(const f32x4*)(p + 4);
            bf16x8 fr;
            fr[0]=f2bf(p0[0]); fr[1]=f2bf(p0[1]); fr[2]=f2bf(p0[2]); fr[3]=f2bf(p0[3]);
            fr[4]=f2bf(p1[0]); fr[5]=f2bf(p1[1]); fr[6]=f2bf(p1[2]); fr[7]=f2bf(p1[3]);
            a[mt] = fr;
        }
        #pragma unroll
        for (int nt = 0; nt < 2; ++nt) {
            const float* p = w + (size_t)(Nb + nt * 16 + l16) * DM + k0 + quad * 8;
            f32x4 p0 = *(const f32x4*)p;
            f32x4 p1 = *(const f32x4*)(p + 4);
            bf16x8 fr;
            fr[0]=f2bf(p0[0]); fr[1]=f2bf(p0[1]); fr[2]=f2bf(p0[2]); fr[3]=f2bf(p0[3]);
            fr[4]=f2bf(p1[0]); fr[5]=f2bf(p1[1]); fr[6]=f2bf(p1[2]); fr[7]=f2bf(p1[3]);
            b[nt] = fr;
        }
        #pragma unroll
        for (int mt = 0; mt < 2; ++mt)
            #pragma unroll
            for (int nt = 0; nt < 2; ++nt)
                acc[mt][nt] = __builtin_amdgcn_mfma_f32_16x16x32_bf16(a[mt], b[nt], acc[mt][nt], 0, 0, 0);
    }

    // Epilogue: C layout row = quad*4+reg, col = l16. RoPE pairs are adjacent cols -> lane^1.
    #pragma unroll
    for (int mt = 0; mt < 2; ++mt) {
        #pragma unroll
        for (int nt = 0; nt < 2; ++nt) {
            #pragma unroll
            for (int r = 0; r < 4; ++r) {
                int row = Mb + mt * 16 + quad * 4 + r;
                int col = Nb + nt * 16 + l16;
                float val = acc[mt][nt][r];
                float part = __shfl_xor(val, 1, 64);  // partner element of the RoPE pair
                if (do_rope) {
                    int s = row & (SEQ - 1);
                    int pos = tokpos[s];
                    int i = (col & 63) >> 1;
                    float c = cos_t[pos * 32 + i];
                    float sn = sin_t[pos * 32 + i];
                    val = (col & 1) ? (val * c + part * sn) : (val * c - part * sn);
                }
                int bb = row >> 11, s = row & (SEQ - 1);
                int h = col >> 6, d = col & 63;
                dst[(((size_t)(bb * NH + h) * SEQ + s) << 6) + d] = (ushort_t)f2bf(val);
            }
        }
    }
}

// ---------------- Causal flash attention ----------------
// grid (SEQ/16, 32 /*b*NH+h*/), block 64 (one wave). Q/K/V bf16 [b,h,s,d]; out bf16 [b,s,h*64+d].
__global__ __launch_bounds__(64) void attn_kernel(
    const ushort_t* __restrict__ Q, const ushort_t* __restrict__ K,
    const ushort_t* __restrict__ V, ushort_t* __restrict__ O)
{
    __shared__ __align__(16) short lds_p[16 * 32];

    const int lane = threadIdx.x & 63;
    const int quad = lane >> 4, l16 = lane & 15;
    const int bh = blockIdx.y;
    const int q0 = blockIdx.x * 16;

    const ushort_t* Qb = Q + (size_t)bh * SEQ * DKV;
    const ushort_t* Kb = K + (size_t)bh * SEQ * DKV;
    const ushort_t* Vb = V + (size_t)bh * SEQ * DKV;

    // Q A-fragments: A[m=l16][k=quad*8+j], two K-halves of d
    bf16x8 a_q[2];
    #pragma unroll
    for (int half = 0; half < 2; ++half)
        a_q[half] = *(const bf16x8*)(Qb + (size_t)(q0 + l16) * DKV + half * 32 + quad * 8);

    f32x4 acc[4] = {};
    float m_r[4], l_r[4];
    #pragma unroll
    for (int r = 0; r < 4; ++r) { m_r[r] = -INFINITY; l_r[r] = 0.f; }

    const int nkt = (q0 + 16 + 31) >> 5;  // ceil((q0+16)/32)
    for (int kt = 0; kt < nkt; ++kt) {
        const int kbase = kt * 32;

        // S = Q K^T (scaled), two 16x16 n-tiles
        f32x4 s[2];
        #pragma unroll
        for (int nt = 0; nt < 2; ++nt) {
            int kk = kbase + nt * 16 + l16;
            bf16x8 bk0 = *(const bf16x8*)(Kb + (size_t)kk * DKV + 0  + quad * 8);
            bf16x8 bk1 = *(const bf16x8*)(Kb + (size_t)kk * DKV + 32 + quad * 8);
            f32x4 z = {};
            z = __builtin_amdgcn_mfma_f32_16x16x32_bf16(a_q[0], bk0, z, 0, 0, 0);
            z = __builtin_amdgcn_mfma_f32_16x16x32_bf16(a_q[1], bk1, z, 0, 0, 0);
            s[nt] = z;
        }
        // scale + causal mask (C layout: row=quad*4+r, col=l16)
        #pragma unroll
        for (int nt = 0; nt < 2; ++nt) {
            int kk = kbase + nt * 16 + l16;
            #pragma unroll
            for (int r = 0; r < 4; ++r) {
                int qrow = q0 + quad * 4 + r;
                s[nt][r] = (kk <= qrow) ? s[nt][r] * 0.125f : -INFINITY;
            }
        }
        // per-row max over 32 cols (16 lanes share a row)
        float mx[4];
        #pragma unroll
        for (int r = 0; r < 4; ++r) mx[r] = fmaxf(s[0][r], s[1][r]);
        #pragma unroll
        for (int off = 1; off < 16; off <<= 1)
            #pragma unroll
            for (int r = 0; r < 4; ++r) mx[r] = fmaxf(mx[r], __shfl_xor(mx[r], off, 64));

        float alpha[4];
        #pragma unroll
        for (int r = 0; r < 4; ++r) {
            float mn = fmaxf(m_r[r], mx[r]);
            alpha[r] = __expf(m_r[r] - mn);
            m_r[r] = mn;
        }
        float p[2][4];
        #pragma unroll
        for (int nt = 0; nt < 2; ++nt)
            #pragma unroll
            for (int r = 0; r < 4; ++r) p[nt][r] = __expf(s[nt][r] - m_r[r]);

        float rs[4];
        #pragma unroll
        for (int r = 0; r < 4; ++r) rs[r] = p[0][r] + p[1][r];
        #pragma unroll
        for (int off = 1; off < 16; off <<= 1)
            #pragma unroll
            for (int r = 0; r < 4; ++r) rs[r] += __shfl_xor(rs[r], off, 64);
        #pragma unroll
        for (int r = 0; r < 4; ++r) l_r[r] = l_r[r] * alpha[r] + rs[r];
        #pragma unroll
        for (int dnt = 0; dnt < 4; ++dnt)
            #pragma unroll
            for (int r = 0; r < 4; ++r) acc[dnt][r] *= alpha[r];

        // P: C-layout -> LDS -> A-layout (bf16)
        __syncthreads();
        #pragma unroll
        for (int nt = 0; nt < 2; ++nt)
            #pragma unroll
            for (int r = 0; r < 4; ++r)
                lds_p[(quad * 4 + r) * 32 + nt * 16 + l16] = f2bf(p[nt][r]);
        __syncthreads();
        bf16x8 a_p = *(const bf16x8*)&lds_p[l16 * 32 + quad * 8];

        // O += P V : B[k=kk_local][n=d] = V[kbase+kk_local][d]
        #pragma unroll
        for (int dnt = 0; dnt < 4; ++dnt) {
            bf16x8 bv;
            #pragma unroll
            for (int j = 0; j < 8; ++j)
                bv[j] = (short)Vb[(size_t)(kbase + quad * 8 + j) * DKV + dnt * 16 + l16];
            acc[dnt] = __builtin_amdgcn_mfma_f32_16x16x32_bf16(a_p, bv, acc[dnt], 0, 0, 0);
        }
    }

    // epilogue: O /= l, write [b, s, h*64+d]
    const int bb = bh >> 4, h = bh & 15;
    float inv[4];
    #pragma unroll
    for (int r = 0; r < 4; ++r) inv[r] = 1.0f / l_r[r];
    #pragma unroll
    for (int dnt = 0; dnt < 4; ++dnt)
        #pragma unroll
        for (int r = 0; r < 4; ++r) {
            int qrow = q0 + quad * 4 + r;
            int d = dnt * 16 + l16;
            O[(size_t)(bb * SEQ + qrow) * DM + h * DKV + d] = (ushort_t)f2bf(acc[dnt][r] * inv[r]);
        }
}

// ---------------- Output projection: out = AO * Wo^T (AO bf16, Wo fp32, out fp32) ----------------
__global__ __launch_bounds__(256) void oproj_kernel(
    const ushort_t* __restrict__ A, const float* __restrict__ w, float* __restrict__ out)
{
    const int lane = threadIdx.x & 63;
    const int wave = threadIdx.x >> 6;
    const int quad = lane >> 4, l16 = lane & 15;
    const int Mb = blockIdx.y * 64 + (wave >> 1) * 32;
    const int Nb = blockIdx.x * 64 + (wave & 1) * 32;

    f32x4 acc[2][2] = {};
    for (int k0 = 0; k0 < DM; k0 += 32) {
        bf16x8 a[2], b[2];
        #pragma unroll
        for (int mt = 0; mt < 2; ++mt)
            a[mt] = *(const bf16x8*)(A + (size_t)(Mb + mt * 16 + l16) * DM + k0 + quad * 8);
        #pragma unroll
        for (int nt = 0; nt < 2; ++nt) {
            const float* p = w + (size_t)(Nb + nt * 16 + l16) * DM + k0 + quad * 8;
            f32x4 p0 = *(const f32x4*)p;
            f32x4 p1 = *(const f32x4*)(p + 4);
            bf16x8 fr;
            fr[0]=f2bf(p0[0]); fr[1]=f2bf(p0[1]); fr[2]=f2bf(p0[2]); fr[3]=f2bf(p0[3]);
            fr[4]=f2bf(p1[0]); fr[5]=f2bf(p1[1]); fr[6]=f2bf(p1[2]); fr[7]=f2bf(p1[3]);
            b[nt] = fr;
        }
        #pragma unroll
        for (int mt = 0; mt < 2; ++mt)
            #pragma unroll
            for (int nt = 0; nt < 2; ++nt)
                acc[mt][nt] = __builtin_amdgcn_mfma_f32_16x16x32_bf16(a[mt], b[nt], acc[mt][nt], 0, 0, 0);
    }
    #pragma unroll
    for (int mt = 0; mt < 2; ++mt)
        #pragma unroll
        for (int nt = 0; nt < 2; ++nt)
            #pragma unroll
            for (int r = 0; r < 4; ++r) {
                int row = Mb + mt * 16 + quad * 4 + r;
                int col = Nb + nt * 16 + l16;
                out[(size_t)row * DM + col] = acc[mt][nt][r];
            }
}

extern "C" void kernel_launch(void* const* d_in, const int* in_sizes, int n_in,
                              void* d_out, int out_size, void* d_ws, size_t ws_size,
                              hipStream_t stream) {
    const float* x  = (const float*)d_in[0];
    const float* wq = (const float*)d_in[1];
    const float* wk = (const float*)d_in[2];
    const float* wv = (const float*)d_in[3];
    const float* wo = (const float*)d_in[4];
    const int* tokpos = (const int*)d_in[5];
    float* out = (float*)d_out;

    char* ws = (char*)d_ws;
    float* cos_t = (float*)ws;                         // 2048*32*4 = 256 KB
    float* sin_t = (float*)(ws + 256 * 1024);          // 256 KB
    ushort_t* Qb = (ushort_t*)(ws + 512 * 1024);       // 8 MB each
    ushort_t* Kb = Qb + (size_t)MTOT * DM;
    ushort_t* Vb = Kb + (size_t)MTOT * DM;
    ushort_t* AO = Vb + (size_t)MTOT * DM;             // total ~32.5 MB

    rope_table_kernel<<<256, 256, 0, stream>>>(cos_t, sin_t);
    proj_qkv_kernel<<<dim3(DM / 64, MTOT / 64, 3), 256, 0, stream>>>(
        x, wq, wk, wv, cos_t, sin_t, tokpos, Qb, Kb, Vb);
    attn_kernel<<<dim3(SEQ / 16, 32), 64, 0, stream>>>(Qb, Kb, Vb, AO);
    oproj_kernel<<<dim3(DM / 64, MTOT / 64), 256, 0, stream>>>(AO, wo, out);
}

// Round 2
// 350.085 us; speedup vs baseline: 2.0217x; 2.0217x over previous
//
#include <hip/hip_runtime.h>
#include <math.h>

#define SEQ 2048
#define DM 1024
#define NH 16
#define DKV 64
#define MTOT 4096  /* BATCH*SEQ */
#define PD 40      /* padded LDS row stride (shorts) for 32-col bf16 tiles: 80B = 2-way free on frag reads */

typedef __attribute__((ext_vector_type(8))) short bf16x8;
typedef __attribute__((ext_vector_type(4))) short s16x4;
typedef __attribute__((ext_vector_type(4))) float f32x4;
typedef unsigned short ushort_t;

__device__ __forceinline__ short f2bf(float f) {
    union { float f; unsigned u; } v; v.f = f;
    unsigned r = v.u + 0x7fffu + ((v.u >> 16) & 1u);
    return (short)(r >> 16);
}

__device__ __forceinline__ bf16x8 cvt8(f32x4 a, f32x4 b) {
    bf16x8 r;
    r[0]=f2bf(a[0]); r[1]=f2bf(a[1]); r[2]=f2bf(a[2]); r[3]=f2bf(a[3]);
    r[4]=f2bf(b[0]); r[5]=f2bf(b[1]); r[6]=f2bf(b[2]); r[7]=f2bf(b[3]);
    return r;
}

// ---------------- RoPE tables: cos/sin[pos][i], pos<2048, i<32 ----------------
__global__ void rope_table_kernel(float* __restrict__ cos_t, float* __restrict__ sin_t) {
    int tid = blockIdx.x * blockDim.x + threadIdx.x;  // 0..65535
    int i = tid & 31, pos = tid >> 5;
    double freq = pow(10000.0, -(double)(2 * i) / 64.0);
    double ang = (double)pos * freq;
    cos_t[tid] = (float)cos(ang);
    sin_t[tid] = (float)sin(ang);
}

// ---------------- Fused QKV projection + RoPE + V-transpose ----------------
// C = X * W^T over fused N=3072 (q|k|v). grid (3072/128, 4096/128), block 256.
// m93-style: 128x128 tile, BK=32, stage-convert fp32->bf16 into padded LDS.
__global__ __launch_bounds__(256) void proj_qkv_kernel(
    const float* __restrict__ x,
    const float* __restrict__ wq, const float* __restrict__ wk, const float* __restrict__ wv,
    const float* __restrict__ cos_t, const float* __restrict__ sin_t,
    const int* __restrict__ tokpos,
    ushort_t* __restrict__ Qg, ushort_t* __restrict__ Kg, ushort_t* __restrict__ Vt)
{
    __shared__ __align__(16) short lA[128 * PD];
    __shared__ __align__(16) short lB[128 * PD];

    const int t = threadIdx.x;
    const int lane = t & 63;
    const int wave = t >> 6;
    const int quad = lane >> 4, l16 = lane & 15;
    const int mh = wave >> 1, nh = wave & 1;   // 64x64 quadrant per wave
    const int Mb = blockIdx.y * 128;
    const int NbG = blockIdx.x * 128;          // fused col 0..3071
    const int z = NbG >> 10;                   // 0=q 1=k 2=v (block-uniform)
    const int Nb = NbG & 1023;
    const float* w = (z == 0) ? wq : (z == 1) ? wk : wv;

    const int srow = t >> 1;                   // staging: 0..127
    const int shalf = t & 1;                   // 16-float half of the 32-col row

    f32x4 acc[4][4] = {};

    for (int k0 = 0; k0 < DM; k0 += 32) {
        __syncthreads();
        {   // stage A (x)
            const float* p = x + (size_t)(Mb + srow) * DM + k0 + shalf * 16;
            f32x4 q0 = ((const f32x4*)p)[0], q1 = ((const f32x4*)p)[1];
            f32x4 q2 = ((const f32x4*)p)[2], q3 = ((const f32x4*)p)[3];
            *(bf16x8*)&lA[srow * PD + shalf * 16]     = cvt8(q0, q1);
            *(bf16x8*)&lA[srow * PD + shalf * 16 + 8] = cvt8(q2, q3);
        }
        {   // stage B (w)
            const float* p = w + (size_t)(Nb + srow) * DM + k0 + shalf * 16;
            f32x4 q0 = ((const f32x4*)p)[0], q1 = ((const f32x4*)p)[1];
            f32x4 q2 = ((const f32x4*)p)[2], q3 = ((const f32x4*)p)[3];
            *(bf16x8*)&lB[srow * PD + shalf * 16]     = cvt8(q0, q1);
            *(bf16x8*)&lB[srow * PD + shalf * 16 + 8] = cvt8(q2, q3);
        }
        __syncthreads();

        bf16x8 a[4], b[4];
        #pragma unroll
        for (int mt = 0; mt < 4; ++mt)
            a[mt] = *(const bf16x8*)&lA[(mh * 64 + mt * 16 + l16) * PD + quad * 8];
        #pragma unroll
        for (int nt = 0; nt < 4; ++nt)
            b[nt] = *(const bf16x8*)&lB[(nh * 64 + nt * 16 + l16) * PD + quad * 8];
        #pragma unroll
        for (int mt = 0; mt < 4; ++mt)
            #pragma unroll
            for (int nt = 0; nt < 4; ++nt)
                acc[mt][nt] = __builtin_amdgcn_mfma_f32_16x16x32_bf16(a[mt], b[nt], acc[mt][nt], 0, 0, 0);
    }

    // Epilogue. C layout: row = quad*4+r, col = l16. Block rows stay within one batch (2048 | Mb).
    const int bb = Mb >> 11;
    if (z == 2) {
        // V: store transposed Vt[b,h,d,s], pack 4 consecutive s into one 8B store
        #pragma unroll
        for (int mt = 0; mt < 4; ++mt) {
            const int s0 = (Mb + mh * 64 + mt * 16 + quad * 4) & (SEQ - 1);
            #pragma unroll
            for (int nt = 0; nt < 4; ++nt) {
                int col = Nb + nh * 64 + nt * 16 + l16;
                int h = col >> 6, d = col & 63;
                s16x4 pk;
                #pragma unroll
                for (int r = 0; r < 4; ++r) pk[r] = f2bf(acc[mt][nt][r]);
                *(s16x4*)&Vt[((size_t)(bb * NH + h) * DKV + d) * SEQ + s0] = pk;
            }
        }
    } else {
        ushort_t* dst = (z == 0) ? Qg : Kg;
        #pragma unroll
        for (int mt = 0; mt < 4; ++mt) {
            #pragma unroll
            for (int nt = 0; nt < 4; ++nt) {
                #pragma unroll
                for (int r = 0; r < 4; ++r) {
                    int row = Mb + mh * 64 + mt * 16 + quad * 4 + r;
                    int s = row & (SEQ - 1);
                    int col = Nb + nh * 64 + nt * 16 + l16;
                    int h = col >> 6, d = col & 63;
                    float val = acc[mt][nt][r];
                    float part = __shfl_xor(val, 1, 64);  // RoPE pair partner (adjacent col = adjacent lane)
                    int pos = tokpos[s];
                    int i = d >> 1;
                    float c = cos_t[pos * 32 + i];
                    float sn = sin_t[pos * 32 + i];
                    val = (d & 1) ? (val * c + part * sn) : (val * c - part * sn);
                    dst[((size_t)(bb * NH + h) * SEQ + s) * DKV + d] = (ushort_t)f2bf(val);
                }
            }
        }
    }
}

// ---------------- Causal flash attention ----------------
// grid (SEQ/32, 32 /*b*NH+h*/), block 64 (one wave), 32 q-rows per wave.
// Q,K bf16 [b,h,s,d]; Vt bf16 [b,h,d,s]; out AO bf16 [b,s,h*64+d].
__global__ __launch_bounds__(64) void attn_kernel(
    const ushort_t* __restrict__ Q, const ushort_t* __restrict__ K,
    const ushort_t* __restrict__ Vt, ushort_t* __restrict__ O)
{
    __shared__ __align__(16) short lds_p[32 * PD];

    const int lane = threadIdx.x & 63;
    const int quad = lane >> 4, l16 = lane & 15;
    const int bh = blockIdx.y;
    const int q0 = blockIdx.x * 32;

    const ushort_t* Qb = Q + (size_t)bh * SEQ * DKV;
    const ushort_t* Kb = K + (size_t)bh * SEQ * DKV;
    const ushort_t* Vtb = Vt + (size_t)bh * DKV * SEQ;

    bf16x8 a_q[2][2];
    #pragma unroll
    for (int mt = 0; mt < 2; ++mt)
        #pragma unroll
        for (int half = 0; half < 2; ++half)
            a_q[mt][half] = *(const bf16x8*)(Qb + (size_t)(q0 + mt * 16 + l16) * DKV + half * 32 + quad * 8);

    f32x4 acc[2][4] = {};
    float m_r[2][4], l_r[2][4];
    #pragma unroll
    for (int mt = 0; mt < 2; ++mt)
        #pragma unroll
        for (int r = 0; r < 4; ++r) { m_r[mt][r] = -INFINITY; l_r[mt][r] = 0.f; }

    const int nkt = (q0 >> 5) + 1;
    for (int kt = 0; kt < nkt; ++kt) {
        const int kbase = kt * 32;
        const bool last = (kt == nkt - 1);

        // S = Q K^T
        bf16x8 bk[2][2];
        #pragma unroll
        for (int nt = 0; nt < 2; ++nt)
            #pragma unroll
            for (int half = 0; half < 2; ++half)
                bk[nt][half] = *(const bf16x8*)(Kb + (size_t)(kbase + nt * 16 + l16) * DKV + half * 32 + quad * 8);
        f32x4 s[2][2];
        #pragma unroll
        for (int mt = 0; mt < 2; ++mt)
            #pragma unroll
            for (int nt = 0; nt < 2; ++nt) {
                f32x4 zz = {};
                zz = __builtin_amdgcn_mfma_f32_16x16x32_bf16(a_q[mt][0], bk[nt][0], zz, 0, 0, 0);
                zz = __builtin_amdgcn_mfma_f32_16x16x32_bf16(a_q[mt][1], bk[nt][1], zz, 0, 0, 0);
                s[mt][nt] = zz;
            }

        // scale + causal mask (only needed on the diagonal tile)
        #pragma unroll
        for (int mt = 0; mt < 2; ++mt)
            #pragma unroll
            for (int nt = 0; nt < 2; ++nt) {
                int kk = kbase + nt * 16 + l16;
                #pragma unroll
                for (int r = 0; r < 4; ++r) {
                    float v = s[mt][nt][r] * 0.125f;
                    if (last && kk > q0 + mt * 16 + quad * 4 + r) v = -INFINITY;
                    s[mt][nt][r] = v;
                }
            }

        // online softmax per 16-row group
        float p[2][2][4];
        #pragma unroll
        for (int mt = 0; mt < 2; ++mt) {
            float mx[4];
            #pragma unroll
            for (int r = 0; r < 4; ++r) mx[r] = fmaxf(s[mt][0][r], s[mt][1][r]);
            #pragma unroll
            for (int off = 1; off < 16; off <<= 1)
                #pragma unroll
                for (int r = 0; r < 4; ++r) mx[r] = fmaxf(mx[r], __shfl_xor(mx[r], off, 64));
            float alpha[4];
            #pragma unroll
            for (int r = 0; r < 4; ++r) {
                float mn = fmaxf(m_r[mt][r], mx[r]);
                alpha[r] = __expf(m_r[mt][r] - mn);
                m_r[mt][r] = mn;
            }
            #pragma unroll
            for (int nt = 0; nt < 2; ++nt)
                #pragma unroll
                for (int r = 0; r < 4; ++r) p[mt][nt][r] = __expf(s[mt][nt][r] - m_r[mt][r]);
            float rs[4];
            #pragma unroll
            for (int r = 0; r < 4; ++r) rs[r] = p[mt][0][r] + p[mt][1][r];
            #pragma unroll
            for (int off = 1; off < 16; off <<= 1)
                #pragma unroll
                for (int r = 0; r < 4; ++r) rs[r] += __shfl_xor(rs[r], off, 64);
            #pragma unroll
            for (int r = 0; r < 4; ++r) l_r[mt][r] = l_r[mt][r] * alpha[r] + rs[r];
            #pragma unroll
            for (int dnt = 0; dnt < 4; ++dnt)
                #pragma unroll
                for (int r = 0; r < 4; ++r) acc[mt][dnt][r] *= alpha[r];
        }

        // P: C-layout -> LDS -> A-layout
        __syncthreads();
        #pragma unroll
        for (int mt = 0; mt < 2; ++mt)
            #pragma unroll
            for (int nt = 0; nt < 2; ++nt)
                #pragma unroll
                for (int r = 0; r < 4; ++r)
                    lds_p[(mt * 16 + quad * 4 + r) * PD + nt * 16 + l16] = f2bf(p[mt][nt][r]);
        __syncthreads();
        bf16x8 a_p[2];
        #pragma unroll
        for (int mt = 0; mt < 2; ++mt)
            a_p[mt] = *(const bf16x8*)&lds_p[(mt * 16 + l16) * PD + quad * 8];

        // O += P V via Vt (16B contiguous B-frag loads)
        #pragma unroll
        for (int dnt = 0; dnt < 4; ++dnt) {
            bf16x8 bv = *(const bf16x8*)(Vtb + (size_t)(dnt * 16 + l16) * SEQ + kbase + quad * 8);
            #pragma unroll
            for (int mt = 0; mt < 2; ++mt)
                acc[mt][dnt] = __builtin_amdgcn_mfma_f32_16x16x32_bf16(a_p[mt], bv, acc[mt][dnt], 0, 0, 0);
        }
    }

    // epilogue
    const int bb = bh >> 4, h = bh & 15;
    #pragma unroll
    for (int mt = 0; mt < 2; ++mt) {
        float inv[4];
        #pragma unroll
        for (int r = 0; r < 4; ++r) inv[r] = 1.0f / l_r[mt][r];
        #pragma unroll
        for (int dnt = 0; dnt < 4; ++dnt)
            #pragma unroll
            for (int r = 0; r < 4; ++r) {
                int qrow = q0 + mt * 16 + quad * 4 + r;
                int d = dnt * 16 + l16;
                O[(size_t)(bb * SEQ + qrow) * DM + h * DKV + d] = (ushort_t)f2bf(acc[mt][dnt][r] * inv[r]);
            }
    }
}

// ---------------- Output projection: out = AO * Wo^T (AO bf16, Wo fp32, out fp32) ----------------
__global__ __launch_bounds__(256) void oproj_kernel(
    const ushort_t* __restrict__ A, const float* __restrict__ w, float* __restrict__ out)
{
    __shared__ __align__(16) short lA[128 * PD];
    __shared__ __align__(16) short lB[128 * PD];

    const int t = threadIdx.x;
    const int lane = t & 63;
    const int wave = t >> 6;
    const int quad = lane >> 4, l16 = lane & 15;
    const int mh = wave >> 1, nh = wave & 1;
    const int Mb = blockIdx.y * 128;
    const int Nb = blockIdx.x * 128;

    const int srow = t >> 1;
    const int shalf = t & 1;

    f32x4 acc[4][4] = {};

    for (int k0 = 0; k0 < DM; k0 += 32) {
        __syncthreads();
        {   // stage A (bf16, direct)
            const ushort_t* p = A + (size_t)(Mb + srow) * DM + k0 + shalf * 16;
            bf16x8 r0 = ((const bf16x8*)p)[0];
            bf16x8 r1 = ((const bf16x8*)p)[1];
            *(bf16x8*)&lA[srow * PD + shalf * 16]     = r0;
            *(bf16x8*)&lA[srow * PD + shalf * 16 + 8] = r1;
        }
        {   // stage B (fp32 -> bf16)
            const float* p = w + (size_t)(Nb + srow) * DM + k0 + shalf * 16;
            f32x4 q0 = ((const f32x4*)p)[0], q1 = ((const f32x4*)p)[1];
            f32x4 q2 = ((const f32x4*)p)[2], q3 = ((const f32x4*)p)[3];
            *(bf16x8*)&lB[srow * PD + shalf * 16]     = cvt8(q0, q1);
            *(bf16x8*)&lB[srow * PD + shalf * 16 + 8] = cvt8(q2, q3);
        }
        __syncthreads();

        bf16x8 a[4], b[4];
        #pragma unroll
        for (int mt = 0; mt < 4; ++mt)
            a[mt] = *(const bf16x8*)&lA[(mh * 64 + mt * 16 + l16) * PD + quad * 8];
        #pragma unroll
        for (int nt = 0; nt < 4; ++nt)
            b[nt] = *(const bf16x8*)&lB[(nh * 64 + nt * 16 + l16) * PD + quad * 8];
        #pragma unroll
        for (int mt = 0; mt < 4; ++mt)
            #pragma unroll
            for (int nt = 0; nt < 4; ++nt)
                acc[mt][nt] = __builtin_amdgcn_mfma_f32_16x16x32_bf16(a[mt], b[nt], acc[mt][nt], 0, 0, 0);
    }

    #pragma unroll
    for (int mt = 0; mt < 4; ++mt)
        #pragma unroll
        for (int nt = 0; nt < 4; ++nt)
            #pragma unroll
            for (int r = 0; r < 4; ++r) {
                int row = Mb + mh * 64 + mt * 16 + quad * 4 + r;
                int col = Nb + nh * 64 + nt * 16 + l16;
                out[(size_t)row * DM + col] = acc[mt][nt][r];
            }
}

extern "C" void kernel_launch(void* const* d_in, const int* in_sizes, int n_in,
                              void* d_out, int out_size, void* d_ws, size_t ws_size,
                              hipStream_t stream) {
    const float* x  = (const float*)d_in[0];
    const float* wq = (const float*)d_in[1];
    const float* wk = (const float*)d_in[2];
    const float* wv = (const float*)d_in[3];
    const float* wo = (const float*)d_in[4];
    const int* tokpos = (const int*)d_in[5];
    float* out = (float*)d_out;

    char* ws = (char*)d_ws;
    float* cos_t = (float*)ws;                         // 256 KB
    float* sin_t = (float*)(ws + 256 * 1024);          // 256 KB
    ushort_t* Qg = (ushort_t*)(ws + 512 * 1024);       // 8 MB each
    ushort_t* Kg = Qg + (size_t)MTOT * DM;
    ushort_t* Vt = Kg + (size_t)MTOT * DM;
    ushort_t* AO = Vt + (size_t)MTOT * DM;             // total 32.5 MB (same as round 1)

    rope_table_kernel<<<256, 256, 0, stream>>>(cos_t, sin_t);
    proj_qkv_kernel<<<dim3(3 * DM / 128, MTOT / 128), 256, 0, stream>>>(
        x, wq, wk, wv, cos_t, sin_t, tokpos, Qg, Kg, Vt);
    attn_kernel<<<dim3(SEQ / 32, 32), 64, 0, stream>>>(Qg, Kg, Vt, AO);
    oproj_kernel<<<dim3(DM / 128, MTOT / 128), 256, 0, stream>>>(AO, wo, out);
}

// Round 3
// 271.120 us; speedup vs baseline: 2.6105x; 1.2913x over previous
//
#include <hip/hip_runtime.h>
#include <math.h>

#define SEQ 2048
#define DM 1024
#define NH 16
#define DKV 64
#define MTOT 4096  /* BATCH*SEQ */
#define PD 40      /* padded LDS row stride (shorts) for the P tile */

typedef __attribute__((ext_vector_type(8))) short bf16x8;
typedef __attribute__((ext_vector_type(4))) short s16x4;
typedef __attribute__((ext_vector_type(4))) float f32x4;
typedef unsigned short ushort_t;

__device__ __forceinline__ short f2bf(float f) {
    union { float f; unsigned u; } v; v.f = f;
    unsigned r = v.u + 0x7fffu + ((v.u >> 16) & 1u);
    return (short)(r >> 16);
}

__device__ __forceinline__ bf16x8 cvt8(f32x4 a, f32x4 b) {
    bf16x8 r;
    r[0]=f2bf(a[0]); r[1]=f2bf(a[1]); r[2]=f2bf(a[2]); r[3]=f2bf(a[3]);
    r[4]=f2bf(b[0]); r[5]=f2bf(b[1]); r[6]=f2bf(b[2]); r[7]=f2bf(b[3]);
    return r;
}

// async global->LDS, 16B per lane. LDS dest = wave-uniform base + lane*16.
__device__ __forceinline__ void gload_lds16(const void* g, void* l) {
    __builtin_amdgcn_global_load_lds(
        (const __attribute__((address_space(1))) unsigned int*)g,
        (__attribute__((address_space(3))) unsigned int*)l, 16, 0, 0);
}

// ---------------- fp32 -> bf16 weight fuse: Wqkv[3072][1024] = wq|wk|wv ----------------
__global__ void cvt_kernel(const float* __restrict__ wq, const float* __restrict__ wk,
                           const float* __restrict__ wv, ushort_t* __restrict__ Wqkv) {
    int tid = blockIdx.x * blockDim.x + threadIdx.x;   // 0..393215
    int z = tid >> 17;                                  // 131072 threads per 1M-el matrix
    int off = (tid & 131071) * 8;
    const float* src = (z == 0) ? wq : (z == 1) ? wk : wv;
    f32x4 a = ((const f32x4*)(src + off))[0];
    f32x4 b = ((const f32x4*)(src + off))[1];
    *(bf16x8*)&Wqkv[(size_t)z * 1048576 + off] = cvt8(a, b);
}

// ---------------- RoPE tables ----------------
__global__ void rope_table_kernel(float* __restrict__ cos_t, float* __restrict__ sin_t) {
    int tid = blockIdx.x * blockDim.x + threadIdx.x;  // 0..65535
    int i = tid & 31, pos = tid >> 5;
    double freq = pow(10000.0, -(double)(2 * i) / 64.0);
    double ang = (double)pos * freq;
    cos_t[tid] = (float)cos(ang);
    sin_t[tid] = (float)sin(ang);
}

// ---------------- Fused QKV projection + RoPE + V-transpose ----------------
// C = X * Wqkv^T. grid (3072/128, 4096/128), block 256. 128x128 tile, BK=32.
// B staged via global_load_lds (bf16), A stage-converted fp32->bf16 by VALU.
// LDS layout: 128 rows x 4 chunks(16B), phys chunk = row*4 + (gchunk ^ ((row>>1)&3)) -> 2-way frag reads.
__global__ __launch_bounds__(256) void proj_qkv_kernel(
    const float* __restrict__ x, const ushort_t* __restrict__ Wqkv,
    const float* __restrict__ cos_t, const float* __restrict__ sin_t,
    const int* __restrict__ tokpos,
    ushort_t* __restrict__ Qg, ushort_t* __restrict__ Kg, ushort_t* __restrict__ Vt)
{
    __shared__ __align__(16) short lA[128 * 32];
    __shared__ __align__(16) short lB[128 * 32];

    const int t = threadIdx.x;
    const int lane = t & 63;
    const int wid = t >> 6;
    const int quad = lane >> 4, l16 = lane & 15;
    const int mh = wid >> 1, nh = wid & 1;
    const int Mb = blockIdx.y * 128;
    const int NbG = blockIdx.x * 128;
    const int z = NbG >> 10;
    const int Nb = NbG & 1023;

    f32x4 acc[4][4] = {};

    for (int k0 = 0; k0 < DM; k0 += 32) {
        __syncthreads();
        // stage B (bf16 weights) via global_load_lds: wave stages rows wid*32..+31 (2x16 rows)
        #pragma unroll
        for (int j = 0; j < 2; ++j) {
            int rbase = wid * 32 + j * 16;
            int row = rbase + (lane >> 2);
            int gch = (lane & 3) ^ ((lane >> 3) & 3);
            gload_lds16(Wqkv + (size_t)(NbG + row) * DM + k0 + gch * 8, &lB[rbase * 32]);
        }
        // stage A (x fp32 -> bf16): thread handles phys chunks t, t+256
        #pragma unroll
        for (int j = 0; j < 2; ++j) {
            int c = t + j * 256;
            int row = c >> 2, slot = c & 3;
            int gch = slot ^ ((c >> 3) & 3);
            const float* p = x + (size_t)(Mb + row) * DM + k0 + gch * 8;
            f32x4 q0 = ((const f32x4*)p)[0], q1 = ((const f32x4*)p)[1];
            *(bf16x8*)&lA[c * 8] = cvt8(q0, q1);
        }
        __syncthreads();

        bf16x8 a[4], b[4];
        #pragma unroll
        for (int mt = 0; mt < 4; ++mt) {
            int row = mh * 64 + mt * 16 + l16;
            int slot = quad ^ ((l16 >> 1) & 3);
            a[mt] = *(const bf16x8*)&lA[row * 32 + slot * 8];
        }
        #pragma unroll
        for (int nt = 0; nt < 4; ++nt) {
            int row = nh * 64 + nt * 16 + l16;
            int slot = quad ^ ((l16 >> 1) & 3);
            b[nt] = *(const bf16x8*)&lB[row * 32 + slot * 8];
        }
        #pragma unroll
        for (int mt = 0; mt < 4; ++mt)
            #pragma unroll
            for (int nt = 0; nt < 4; ++nt)
                acc[mt][nt] = __builtin_amdgcn_mfma_f32_16x16x32_bf16(a[mt], b[nt], acc[mt][nt], 0, 0, 0);
    }

    const int bb = Mb >> 11;
    if (z == 2) {
        #pragma unroll
        for (int mt = 0; mt < 4; ++mt) {
            const int s0 = (Mb + mh * 64 + mt * 16 + quad * 4) & (SEQ - 1);
            #pragma unroll
            for (int nt = 0; nt < 4; ++nt) {
                int col = Nb + nh * 64 + nt * 16 + l16;
                int h = col >> 6, d = col & 63;
                s16x4 pk;
                #pragma unroll
                for (int r = 0; r < 4; ++r) pk[r] = f2bf(acc[mt][nt][r]);
                *(s16x4*)&Vt[((size_t)(bb * NH + h) * DKV + d) * SEQ + s0] = pk;
            }
        }
    } else {
        ushort_t* dst = (z == 0) ? Qg : Kg;
        #pragma unroll
        for (int mt = 0; mt < 4; ++mt) {
            #pragma unroll
            for (int nt = 0; nt < 4; ++nt) {
                #pragma unroll
                for (int r = 0; r < 4; ++r) {
                    int row = Mb + mh * 64 + mt * 16 + quad * 4 + r;
                    int s = row & (SEQ - 1);
                    int col = Nb + nh * 64 + nt * 16 + l16;
                    int h = col >> 6, d = col & 63;
                    float val = acc[mt][nt][r];
                    float part = __shfl_xor(val, 1, 64);
                    int pos = tokpos[s];
                    int i = d >> 1;
                    float c = cos_t[pos * 32 + i];
                    float sn = sin_t[pos * 32 + i];
                    val = (d & 1) ? (val * c + part * sn) : (val * c - part * sn);
                    dst[((size_t)(bb * NH + h) * SEQ + s) * DKV + d] = (ushort_t)f2bf(val);
                }
            }
        }
    }
}

// ---------------- Causal flash attention ----------------
// grid (SEQ/64, 32), block 128 (2 waves x 32 q-rows). Fixed m=0 softmax (scores are O(1),
// exp can't overflow), deferred l-reduction, dbuf LDS K/V via global_load_lds, swizzled.
__device__ __forceinline__ void attn_stage(
    const ushort_t* Kb, const ushort_t* Vtb, short* lK, short* lV,
    int kbase, int wid, int lane)
{
    // K tile: 32 rows x 8 chunks, phys chunk = row*8 + (gch ^ (row&7))
    #pragma unroll
    for (int j = 0; j < 2; ++j) {
        int rbase = wid * 16 + j * 8;
        int row = rbase + (lane >> 3);
        int gch = (lane & 7) ^ ((lane >> 3) & 7);
        gload_lds16(Kb + (size_t)(kbase + row) * DKV + gch * 8, &lK[rbase * 64]);
    }
    // V^T tile: 64 rows(d) x 4 chunks(s), phys chunk = row*4 + (gch ^ ((row>>1)&3))
    #pragma unroll
    for (int j = 0; j < 2; ++j) {
        int rbase = wid * 32 + j * 16;
        int row = rbase + (lane >> 2);
        int gch = (lane & 3) ^ ((lane >> 3) & 3);
        gload_lds16(Vtb + (size_t)row * SEQ + kbase + gch * 8, &lV[rbase * 32]);
    }
}

__global__ __launch_bounds__(128) void attn_kernel(
    const ushort_t* __restrict__ Q, const ushort_t* __restrict__ K,
    const ushort_t* __restrict__ Vt, ushort_t* __restrict__ O)
{
    __shared__ __align__(16) short lK[2][32 * 64];
    __shared__ __align__(16) short lV[2][64 * 32];
    __shared__ __align__(16) short lP[2][32 * PD];

    const int t = threadIdx.x;
    const int lane = t & 63;
    const int wid = t >> 6;
    const int quad = lane >> 4, l16 = lane & 15;
    const int bh = blockIdx.y;
    const int qt = gridDim.x - 1 - blockIdx.x;   // longest blocks dispatch first
    const int q0b = qt * 64;
    const int q0w = q0b + wid * 32;

    const ushort_t* Qb = Q + (size_t)bh * SEQ * DKV;
    const ushort_t* Kb = K + (size_t)bh * SEQ * DKV;
    const ushort_t* Vtb = Vt + (size_t)bh * DKV * SEQ;

    bf16x8 a_q[2][2];
    #pragma unroll
    for (int mt = 0; mt < 2; ++mt)
        #pragma unroll
        for (int half = 0; half < 2; ++half)
            a_q[mt][half] = *(const bf16x8*)(Qb + (size_t)(q0w + mt * 16 + l16) * DKV + half * 32 + quad * 8);

    f32x4 acc[2][4] = {};
    float ps[2][4] = {};   // per-lane partial row-sums (deferred l)

    const int nkt = (q0b >> 5) + 2;
    attn_stage(Kb, Vtb, lK[0], lV[0], 0, wid, lane);

    for (int kt = 0; kt < nkt; ++kt) {
        const int kbase = kt * 32;
        __syncthreads();   // drains staging of tile kt; all waves done reading buf[(kt+1)&1]
        if (kt + 1 < nkt)
            attn_stage(Kb, Vtb, lK[(kt + 1) & 1], lV[(kt + 1) & 1], kbase + 32, wid, lane);

        const short* bK = lK[kt & 1];
        const short* bV = lV[kt & 1];

        // K frags (swizzled, 2-way free)
        bf16x8 bk[2][2];
        #pragma unroll
        for (int nt = 0; nt < 2; ++nt)
            #pragma unroll
            for (int half = 0; half < 2; ++half) {
                int slot = (half * 4 + quad) ^ (l16 & 7);
                bk[nt][half] = *(const bf16x8*)&bK[(nt * 16 + l16) * 64 + slot * 8];
            }

        f32x4 s[2][2];
        #pragma unroll
        for (int mt = 0; mt < 2; ++mt)
            #pragma unroll
            for (int nt = 0; nt < 2; ++nt) {
                f32x4 zz = {};
                zz = __builtin_amdgcn_mfma_f32_16x16x32_bf16(a_q[mt][0], bk[nt][0], zz, 0, 0, 0);
                zz = __builtin_amdgcn_mfma_f32_16x16x32_bf16(a_q[mt][1], bk[nt][1], zz, 0, 0, 0);
                s[mt][nt] = zz;
            }

        // p = exp(s/8), causal mask only where the tile can cross the diagonal
        float p[2][2][4];
        const bool need_mask = (kbase + 31 > q0w);
        #pragma unroll
        for (int mt = 0; mt < 2; ++mt)
            #pragma unroll
            for (int nt = 0; nt < 2; ++nt) {
                int kk = kbase + nt * 16 + l16;
                #pragma unroll
                for (int r = 0; r < 4; ++r) {
                    float pv = __expf(s[mt][nt][r] * 0.125f);
                    if (need_mask && kk > q0w + mt * 16 + quad * 4 + r) pv = 0.f;
                    p[mt][nt][r] = pv;
                    ps[mt][r] += pv;
                }
            }

        // P: C-layout -> per-wave LDS -> A-layout (no barrier needed; region is wave-private)
        #pragma unroll
        for (int mt = 0; mt < 2; ++mt)
            #pragma unroll
            for (int nt = 0; nt < 2; ++nt)
                #pragma unroll
                for (int r = 0; r < 4; ++r)
                    lP[wid][(mt * 16 + quad * 4 + r) * PD + nt * 16 + l16] = f2bf(p[mt][nt][r]);
        bf16x8 a_p[2];
        #pragma unroll
        for (int mt = 0; mt < 2; ++mt)
            a_p[mt] = *(const bf16x8*)&lP[wid][(mt * 16 + l16) * PD + quad * 8];

        // O += P V via swizzled V^T frags
        #pragma unroll
        for (int dnt = 0; dnt < 4; ++dnt) {
            int slot = quad ^ ((l16 >> 1) & 3);
            bf16x8 bv = *(const bf16x8*)&bV[(dnt * 16 + l16) * 32 + slot * 8];
            #pragma unroll
            for (int mt = 0; mt < 2; ++mt)
                acc[mt][dnt] = __builtin_amdgcn_mfma_f32_16x16x32_bf16(a_p[mt], bv, acc[mt][dnt], 0, 0, 0);
        }
    }

    // epilogue: reduce l across the 16 lanes of each row group, normalize, store
    const int bb = bh >> 4, h = bh & 15;
    #pragma unroll
    for (int mt = 0; mt < 2; ++mt) {
        float l[4];
        #pragma unroll
        for (int r = 0; r < 4; ++r) l[r] = ps[mt][r];
        #pragma unroll
        for (int off = 1; off < 16; off <<= 1)
            #pragma unroll
            for (int r = 0; r < 4; ++r) l[r] += __shfl_xor(l[r], off, 64);
        float inv[4];
        #pragma unroll
        for (int r = 0; r < 4; ++r) inv[r] = 1.0f / l[r];
        #pragma unroll
        for (int dnt = 0; dnt < 4; ++dnt)
            #pragma unroll
            for (int r = 0; r < 4; ++r) {
                int qrow = q0w + mt * 16 + quad * 4 + r;
                int d = dnt * 16 + l16;
                O[(size_t)(bb * SEQ + qrow) * DM + h * DKV + d] = (ushort_t)f2bf(acc[mt][dnt][r] * inv[r]);
            }
    }
}

// ---------------- Output projection: out = AO * Wo^T (AO bf16 via global_load_lds, Wo fp32) ----------------
__global__ __launch_bounds__(256) void oproj_kernel(
    const ushort_t* __restrict__ A, const float* __restrict__ w, float* __restrict__ out)
{
    __shared__ __align__(16) short lA[128 * 32];
    __shared__ __align__(16) short lB[128 * 32];

    const int t = threadIdx.x;
    const int lane = t & 63;
    const int wid = t >> 6;
    const int quad = lane >> 4, l16 = lane & 15;
    const int mh = wid >> 1, nh = wid & 1;
    const int Mb = blockIdx.y * 128;
    const int Nb = blockIdx.x * 128;

    f32x4 acc[4][4] = {};

    for (int k0 = 0; k0 < DM; k0 += 32) {
        __syncthreads();
        // stage A (bf16) via global_load_lds
        #pragma unroll
        for (int j = 0; j < 2; ++j) {
            int rbase = wid * 32 + j * 16;
            int row = rbase + (lane >> 2);
            int gch = (lane & 3) ^ ((lane >> 3) & 3);
            gload_lds16(A + (size_t)(Mb + row) * DM + k0 + gch * 8, &lA[rbase * 32]);
        }
        // stage B (wo fp32 -> bf16)
        #pragma unroll
        for (int j = 0; j < 2; ++j) {
            int c = t + j * 256;
            int row = c >> 2, slot = c & 3;
            int gch = slot ^ ((c >> 3) & 3);
            const float* p = w + (size_t)(Nb + row) * DM + k0 + gch * 8;
            f32x4 q0 = ((const f32x4*)p)[0], q1 = ((const f32x4*)p)[1];
            *(bf16x8*)&lB[c * 8] = cvt8(q0, q1);
        }
        __syncthreads();

        bf16x8 a[4], b[4];
        #pragma unroll
        for (int mt = 0; mt < 4; ++mt) {
            int row = mh * 64 + mt * 16 + l16;
            int slot = quad ^ ((l16 >> 1) & 3);
            a[mt] = *(const bf16x8*)&lA[row * 32 + slot * 8];
        }
        #pragma unroll
        for (int nt = 0; nt < 4; ++nt) {
            int row = nh * 64 + nt * 16 + l16;
            int slot = quad ^ ((l16 >> 1) & 3);
            b[nt] = *(const bf16x8*)&lB[row * 32 + slot * 8];
        }
        #pragma unroll
        for (int mt = 0; mt < 4; ++mt)
            #pragma unroll
            for (int nt = 0; nt < 4; ++nt)
                acc[mt][nt] = __builtin_amdgcn_mfma_f32_16x16x32_bf16(a[mt], b[nt], acc[mt][nt], 0, 0, 0);
    }

    #pragma unroll
    for (int mt = 0; mt < 4; ++mt)
        #pragma unroll
        for (int nt = 0; nt < 4; ++nt)
            #pragma unroll
            for (int r = 0; r < 4; ++r) {
                int row = Mb + mh * 64 + mt * 16 + quad * 4 + r;
                int col = Nb + nh * 64 + nt * 16 + l16;
                out[(size_t)row * DM + col] = acc[mt][nt][r];
            }
}

extern "C" void kernel_launch(void* const* d_in, const int* in_sizes, int n_in,
                              void* d_out, int out_size, void* d_ws, size_t ws_size,
                              hipStream_t stream) {
    const float* x  = (const float*)d_in[0];
    const float* wq = (const float*)d_in[1];
    const float* wk = (const float*)d_in[2];
    const float* wv = (const float*)d_in[3];
    const float* wo = (const float*)d_in[4];
    const int* tokpos = (const int*)d_in[5];
    float* out = (float*)d_out;

    // Workspace plan (32 MB total; AO aliases cos/sin/Wqkv, which are dead after proj):
    char* ws = (char*)d_ws;
    float* cos_t    = (float*)ws;                          // 256 KB
    float* sin_t    = (float*)(ws + 256 * 1024);           // 256 KB
    ushort_t* Wqkv  = (ushort_t*)(ws + 512 * 1024);        // 6 MB
    ushort_t* AO    = (ushort_t*)ws;                       // 8 MB (aliases the above)
    ushort_t* Qg    = (ushort_t*)(ws + (size_t)8  * 1024 * 1024);  // 8 MB
    ushort_t* Kg    = (ushort_t*)(ws + (size_t)16 * 1024 * 1024);  // 8 MB
    ushort_t* Vt    = (ushort_t*)(ws + (size_t)24 * 1024 * 1024);  // 8 MB

    cvt_kernel<<<1536, 256, 0, stream>>>(wq, wk, wv, Wqkv);
    rope_table_kernel<<<256, 256, 0, stream>>>(cos_t, sin_t);
    proj_qkv_kernel<<<dim3(3 * DM / 128, MTOT / 128), 256, 0, stream>>>(
        x, Wqkv, cos_t, sin_t, tokpos, Qg, Kg, Vt);
    attn_kernel<<<dim3(SEQ / 64, 32), 128, 0, stream>>>(Qg, Kg, Vt, AO);
    oproj_kernel<<<dim3(DM / 128, MTOT / 128), 256, 0, stream>>>(AO, wo, out);
}